// Round 9
// baseline (199.844 us; speedup 1.0000x reference)
//
#include <hip/hip_runtime.h>

// EdgeLoss: weighted BCE-with-logits mean over 32x1x768x1024 fp32 tensors.
// result = (neg_num * S_pos + pos_num * S_neg) / (pos_num + neg_num) / n
// S_pos = sum over t==1 of bce(x,1), S_neg = sum over t==0 of bce(x,0),
// bce(x,t) = max(x,0) - x*t + log(1+exp(-|x|)).
//
// R8 -> R9: R8 (contiguous per-block segments + NT loads) broke the 78 us
// plateau -> ~55-60 us inferred (stage1 dropped out of top-5; bench total
// 216 -> 198). Access pattern fixed; remaining gap vs the ~6.8 TB/s the
// harness fill kernel demonstrates is prefetch depth (plain load->use,
// vmcnt(0) each iter). Now combine R8's segments with R6's wave-private
// global_load_lds double buffer: DMA uses no VGPRs so the compiler cannot
// collapse the pipeline; wave-local s_waitcnt vmcnt(2) keeps next iter's
// 2 KB in flight during compute; no __syncthreads in the loop. aux=2 sets
// the nt cache-policy bit on the DMA (evict-first, single-use data).

#define GRID1 2048
#define BLOCK 256

typedef float floatx4 __attribute__((ext_vector_type(4)));

// s_waitcnt imm (gfx9 encoding): [3:0] vmcnt lo, [6:4] expcnt, [11:8] lgkmcnt,
// [15:14] vmcnt hi. Don't-care exp=7, lgkm=15.
#define WAITCNT_VM2 0x0F72   // vmcnt(2)
#define WAITCNT_VM0 0x0F70   // vmcnt(0)

__device__ __forceinline__ void dma16nt(const floatx4* g, floatx4* l) {
  __builtin_amdgcn_global_load_lds(
      (const __attribute__((address_space(1))) void*)g,
      (__attribute__((address_space(3))) void*)l, 16, 0, /*aux=nt*/ 2);
}

__device__ __forceinline__ void do_elem(float xv, float tv,
                                        float& cp, float& cn,
                                        float& sp, float& sn) {
  float a = fabsf(xv);
  float e = __expf(-a);                 // v_exp_f32
  float l = __logf(1.0f + e);           // v_log_f32
  float c = fmaxf(xv, 0.f) + l;         // softplus(x) = bce(t==0); bce(t==1)=c-x
  bool pos = (tv == 1.0f);
  bool neg = (tv == 0.0f);
  cp += pos ? 1.0f : 0.0f;
  cn += neg ? 1.0f : 0.0f;
  sp += pos ? (c - xv) : 0.0f;
  sn += neg ? c : 0.0f;
}

__device__ __forceinline__ void do_vec4(floatx4 xv, floatx4 tv,
                                        float& cp, float& cn,
                                        float& sp, float& sn) {
  do_elem(xv.x, tv.x, cp, cn, sp, sn);
  do_elem(xv.y, tv.y, cp, cn, sp, sn);
  do_elem(xv.z, tv.z, cp, cn, sp, sn);
  do_elem(xv.w, tv.w, cp, cn, sp, sn);
}

__global__ __launch_bounds__(BLOCK, 8) void edge_loss_stage1(
    const float* __restrict__ x, const float* __restrict__ t,
    float* __restrict__ partials, long long n) {
  // Wave-private double buffer: [buf][array(x=0,t=1)][thread].
  // DMA dest is wave-uniform base + lane*16: &lds[b][a][wave*64] qualifies.
  __shared__ floatx4 lds[2][2][BLOCK];  // 16 KB/block -> 8 blocks/CU = 128 KB

  long long n4 = n >> 2;
  // Contiguous per-block segment [beg, end) of float4 indices: 2048
  // independent sequential DRAM streams (R8's bank-parallelism win).
  long long per = (n4 + gridDim.x - 1) / gridDim.x;
  long long beg = (long long)blockIdx.x * per;
  long long end = beg + per < n4 ? beg + per : n4;
  long long len = end > beg ? end - beg : 0;
  long long niter = len / BLOCK;        // full 256-wide iterations

  int lane = threadIdx.x & 63;
  int wave = threadIdx.x >> 6;

  const floatx4* __restrict__ x4 = (const floatx4*)x;
  const floatx4* __restrict__ t4 = (const floatx4*)t;

  float cp = 0.f, cn = 0.f, sp = 0.f, sn = 0.f;

  floatx4* lx0 = &lds[0][0][wave * 64];
  floatx4* lt0 = &lds[0][1][wave * 64];
  floatx4* lx1 = &lds[1][0][wave * 64];
  floatx4* lt1 = &lds[1][1][wave * 64];

  // Per-lane global index for iteration k: beg + k*BLOCK + threadIdx.x
  long long g = beg + threadIdx.x;
  if (niter > 0) {
    dma16nt(x4 + g, lx0);               // stage iter 0 into buf 0
    dma16nt(t4 + g, lt0);
  }
  #pragma unroll 1
  for (long long k = 0; k < niter; ++k) {
    int cur = (int)(k & 1);
    if (k + 1 < niter) {
      long long gn = g + BLOCK;         // prefetch iter k+1 into other buf
      dma16nt(x4 + gn, cur ? lx0 : lx1);
      dma16nt(t4 + gn, cur ? lt0 : lt1);
      __builtin_amdgcn_s_waitcnt(WAITCNT_VM2);  // iter k's DMAs done;
                                                // prefetch stays in flight
    } else {
      __builtin_amdgcn_s_waitcnt(WAITCNT_VM0);
    }
    __asm__ volatile("" ::: "memory");  // keep LDS reads below the waitcnt
    floatx4 xv = (cur ? lx1 : lx0)[lane];
    floatx4 tv = (cur ? lt1 : lt0)[lane];
    do_vec4(xv, tv, cp, cn, sp, sn);
    g += BLOCK;
  }
  // remainder of the segment (len % BLOCK threads)
  if (g < end) {
    floatx4 xv = __builtin_nontemporal_load(&x4[g]);
    floatx4 tv = __builtin_nontemporal_load(&t4[g]);
    do_vec4(xv, tv, cp, cn, sp, sn);
  }
  // scalar tail (n not a multiple of 4), grid-stride across all blocks
  for (long long j = (n4 << 2) + (long long)blockIdx.x * BLOCK + threadIdx.x;
       j < n; j += (long long)gridDim.x * BLOCK) {
    do_elem(x[j], t[j], cp, cn, sp, sn);
  }

  // wave-64 shuffle reduction
  #pragma unroll
  for (int off = 32; off > 0; off >>= 1) {
    cp += __shfl_down(cp, off, 64);
    cn += __shfl_down(cn, off, 64);
    sp += __shfl_down(sp, off, 64);
    sn += __shfl_down(sn, off, 64);
  }

  __shared__ float s_cp[4], s_cn[4], s_sp[4], s_sn[4];
  if (lane == 0) { s_cp[wave] = cp; s_cn[wave] = cn; s_sp[wave] = sp; s_sn[wave] = sn; }
  __syncthreads();
  if (threadIdx.x == 0) {
    float tcp = 0.f, tcn = 0.f, tsp = 0.f, tsn = 0.f;
    #pragma unroll
    for (int k = 0; k < 4; ++k) { tcp += s_cp[k]; tcn += s_cn[k]; tsp += s_sp[k]; tsn += s_sn[k]; }
    int G = gridDim.x;
    partials[0 * G + blockIdx.x] = tcp;   // pos count
    partials[1 * G + blockIdx.x] = tcn;   // neg count
    partials[2 * G + blockIdx.x] = tsp;   // sum_pos
    partials[3 * G + blockIdx.x] = tsn;   // sum_neg
  }
}

__global__ __launch_bounds__(BLOCK) void edge_loss_stage2(
    const float* __restrict__ partials, float* __restrict__ out,
    int G, double inv_n) {
  double acc[4] = {0.0, 0.0, 0.0, 0.0};
  for (int i = threadIdx.x; i < G; i += BLOCK) {
    #pragma unroll
    for (int c = 0; c < 4; ++c) acc[c] += (double)partials[c * G + i];
  }
  #pragma unroll
  for (int off = 32; off > 0; off >>= 1) {
    #pragma unroll
    for (int c = 0; c < 4; ++c) acc[c] += __shfl_down(acc[c], off, 64);
  }
  __shared__ double s_acc[4][4];
  int lane = threadIdx.x & 63;
  int wave = threadIdx.x >> 6;
  if (lane == 0) {
    #pragma unroll
    for (int c = 0; c < 4; ++c) s_acc[wave][c] = acc[c];
  }
  __syncthreads();
  if (threadIdx.x == 0) {
    double pos = 0, neg = 0, spos = 0, sneg = 0;
    #pragma unroll
    for (int w = 0; w < 4; ++w) {
      pos += s_acc[w][0]; neg += s_acc[w][1];
      spos += s_acc[w][2]; sneg += s_acc[w][3];
    }
    double s = pos + neg;
    out[0] = (float)((neg * spos + pos * sneg) / s * inv_n);
  }
}

extern "C" void kernel_launch(void* const* d_in, const int* in_sizes, int n_in,
                              void* d_out, int out_size, void* d_ws, size_t ws_size,
                              hipStream_t stream) {
  const float* x = (const float*)d_in[0];
  const float* t = (const float*)d_in[1];
  long long n = (long long)in_sizes[0];
  float* partials = (float*)d_ws;  // 4 * GRID1 floats = 32 KB, fully written

  edge_loss_stage1<<<GRID1, BLOCK, 0, stream>>>(x, t, partials, n);
  edge_loss_stage2<<<1, BLOCK, 0, stream>>>(partials, (float*)d_out,
                                            GRID1, 1.0 / (double)n);
}

// Round 10
// 197.755 us; speedup vs baseline: 1.0106x; 1.0106x over previous
//
#include <hip/hip_runtime.h>

// EdgeLoss: weighted BCE-with-logits mean over 32x1x768x1024 fp32 tensors.
// result = (neg_num * S_pos + pos_num * S_neg) / (pos_num + neg_num) / n
// S_pos = sum over t==1 of bce(x,1), S_neg = sum over t==0 of bce(x,0),
// bce(x,t) = max(x,0) - x*t + log(1+exp(-|x|)).
//
// R9 -> R10: four memory-side mechanisms (reg batch, reg prefetch, LDS-DMA
// dbuf x2) were ALL neutral after R8's contiguous-segment fix -> stage1
// (~55 us) is not memory-concurrency-bound. Arithmetic: ~21 VALU + 2 trans
// per element ~= 30 us of compute vs ~30 us of memory at the demonstrated
// 6.8 TB/s -> balanced pipes, imperfectly overlapped (sum ~= 55 us).
// Now: cut VALU ~30% by reformulating the 4 masked accumulators into
// 5 cheaper ones using t itself as the pos-class weight (t is exactly
// 0/1/2): valid=(t<1.5), tm=valid?t:0;
//   cnt_all+=valid, cnt_pos+=tm, sum_c+=valid?c:0, sum_tc+=tm*c, sum_tx+=tm*x
// stage2 derives pos/neg/S_pos/S_neg exactly. Keep R8 structure (contiguous
// per-block segments + NT loads; no LDS -- R9's DMA path cost 2 us).

#define GRID1 2048
#define BLOCK 256
#define NACC 5

typedef float floatx4 __attribute__((ext_vector_type(4)));

__device__ __forceinline__ void do_elem(float xv, float tv,
                                        float& cnt_all, float& cnt_pos,
                                        float& sum_c, float& sum_tc,
                                        float& sum_tx) {
  float a = fabsf(xv);
  float e = __expf(-a);                  // v_exp_f32
  float l = __logf(1.0f + e);            // v_log_f32
  float c = fmaxf(xv, 0.f) + l;          // softplus(x): bce(t=0)=c, bce(t=1)=c-x
  bool valid = (tv < 1.5f);              // t in {0,1}
  float tm = valid ? tv : 0.0f;          // 1 for pos, 0 otherwise (t exact)
  cnt_all += valid ? 1.0f : 0.0f;
  cnt_pos += tm;
  sum_c   += valid ? c : 0.0f;
  sum_tc   = fmaf(tm, c, sum_tc);
  sum_tx   = fmaf(tm, xv, sum_tx);
}

__device__ __forceinline__ void do_vec4(floatx4 xv, floatx4 tv,
                                        float& a0, float& a1, float& a2,
                                        float& a3, float& a4) {
  do_elem(xv.x, tv.x, a0, a1, a2, a3, a4);
  do_elem(xv.y, tv.y, a0, a1, a2, a3, a4);
  do_elem(xv.z, tv.z, a0, a1, a2, a3, a4);
  do_elem(xv.w, tv.w, a0, a1, a2, a3, a4);
}

__global__ __launch_bounds__(BLOCK, 8) void edge_loss_stage1(
    const float* __restrict__ x, const float* __restrict__ t,
    float* __restrict__ partials, long long n) {
  long long n4 = n >> 2;
  // Contiguous per-block segment [beg, end): 2048 independent sequential
  // DRAM streams (R8's bank-parallelism win).
  long long per = (n4 + gridDim.x - 1) / gridDim.x;
  long long beg = (long long)blockIdx.x * per;
  long long end = beg + per < n4 ? beg + per : n4;

  const floatx4* __restrict__ x4 = (const floatx4*)x;
  const floatx4* __restrict__ t4 = (const floatx4*)t;

  float a0 = 0.f, a1 = 0.f, a2 = 0.f, a3 = 0.f, a4 = 0.f;

  #pragma unroll 2
  for (long long i = beg + threadIdx.x; i < end; i += BLOCK) {
    floatx4 xv = __builtin_nontemporal_load(&x4[i]);
    floatx4 tv = __builtin_nontemporal_load(&t4[i]);
    do_vec4(xv, tv, a0, a1, a2, a3, a4);
  }
  // scalar tail (n not a multiple of 4), grid-stride across all blocks
  for (long long j = (n4 << 2) + (long long)blockIdx.x * BLOCK + threadIdx.x;
       j < n; j += (long long)gridDim.x * BLOCK) {
    do_elem(x[j], t[j], a0, a1, a2, a3, a4);
  }

  // wave-64 shuffle reduction
  #pragma unroll
  for (int off = 32; off > 0; off >>= 1) {
    a0 += __shfl_down(a0, off, 64);
    a1 += __shfl_down(a1, off, 64);
    a2 += __shfl_down(a2, off, 64);
    a3 += __shfl_down(a3, off, 64);
    a4 += __shfl_down(a4, off, 64);
  }

  __shared__ float s_acc[4][NACC];
  int lane = threadIdx.x & 63;
  int wave = threadIdx.x >> 6;
  if (lane == 0) {
    s_acc[wave][0] = a0; s_acc[wave][1] = a1; s_acc[wave][2] = a2;
    s_acc[wave][3] = a3; s_acc[wave][4] = a4;
  }
  __syncthreads();
  if (threadIdx.x == 0) {
    float r[NACC] = {0.f, 0.f, 0.f, 0.f, 0.f};
    #pragma unroll
    for (int w = 0; w < 4; ++w)
      #pragma unroll
      for (int c = 0; c < NACC; ++c) r[c] += s_acc[w][c];
    int G = gridDim.x;
    #pragma unroll
    for (int c = 0; c < NACC; ++c) partials[c * G + blockIdx.x] = r[c];
  }
}

__global__ __launch_bounds__(BLOCK) void edge_loss_stage2(
    const float* __restrict__ partials, float* __restrict__ out,
    int G, double inv_n) {
  double acc[NACC] = {0.0, 0.0, 0.0, 0.0, 0.0};
  for (int i = threadIdx.x; i < G; i += BLOCK) {
    #pragma unroll
    for (int c = 0; c < NACC; ++c) acc[c] += (double)partials[c * G + i];
  }
  #pragma unroll
  for (int off = 32; off > 0; off >>= 1) {
    #pragma unroll
    for (int c = 0; c < NACC; ++c) acc[c] += __shfl_down(acc[c], off, 64);
  }
  __shared__ double s_acc[4][NACC];
  int lane = threadIdx.x & 63;
  int wave = threadIdx.x >> 6;
  if (lane == 0) {
    #pragma unroll
    for (int c = 0; c < NACC; ++c) s_acc[wave][c] = acc[c];
  }
  __syncthreads();
  if (threadIdx.x == 0) {
    double r[NACC] = {0.0, 0.0, 0.0, 0.0, 0.0};
    #pragma unroll
    for (int w = 0; w < 4; ++w)
      #pragma unroll
      for (int c = 0; c < NACC; ++c) r[c] += s_acc[w][c];
    double pos  = r[1];
    double neg  = r[0] - r[1];
    double spos = r[3] - r[4];        // sum_tc - sum_tx
    double sneg = r[2] - r[3];        // sum_c  - sum_tc
    double s = pos + neg;
    out[0] = (float)((neg * spos + pos * sneg) / s * inv_n);
  }
}

extern "C" void kernel_launch(void* const* d_in, const int* in_sizes, int n_in,
                              void* d_out, int out_size, void* d_ws, size_t ws_size,
                              hipStream_t stream) {
  const float* x = (const float*)d_in[0];
  const float* t = (const float*)d_in[1];
  long long n = (long long)in_sizes[0];
  float* partials = (float*)d_ws;  // NACC * GRID1 floats = 40 KB, fully written

  edge_loss_stage1<<<GRID1, BLOCK, 0, stream>>>(x, t, partials, n);
  edge_loss_stage2<<<1, BLOCK, 0, stream>>>(partials, (float*)d_out,
                                            GRID1, 1.0 / (double)n);
}